// Round 6
// baseline (1175.526 us; speedup 1.0000x reference)
//
#include <hip/hip_runtime.h>
#include <cstddef>

// Mamba2 forward, MI355X. bf16 MFMA GEMMs + MFMA ydiag, fp32/bf16 autodetect.
//  0 detect_k / convert_small_k / to_bf16_k(u, W_in)
//  1 gemm256        : zxbcdt = u_b @ Win_b^T    (v6 frag-ahead pipeline)
//  2 conv_silu_k    : causal conv4 + SiLU       (ushort8-vectorized)
//  3 dt_softplus_k  : dt = softplus(raw + dt_bias)
//  4 chunk_states_k : per-chunk cum(dA), decay, states = B^T(decay*dt*x)
//  5 scan_k         : inter-chunk state scan    (512 blocks)
//  6 scores_k       : scores = C.B^T per (b,chunk)
//  7 ydiag_mfma_k   : Y = (scores*L*dt)@x^T + exp(cum)*C@prev^T + D*x  [MFMA]
//  7.5 to_bf16_k(W_out)
//  8 gatenorm_k     : yg = y*silu(z); RMSNorm   (ushort8-vectorized)
//  9 gemm256        : out = yn @ Wout_b^T
//
// gemm256 v6 (frag-ahead): the r2/r5 schedule serialized 24 ds_read_b128
//   against MFMA per K-tile (lgkmcnt(0) before every cluster) -> 36% MfmaUtil.
//   v6 pipelines fragments one phase ahead with COUNTED lgkm waits and ONE
//   barrier per K-tile:
//     ph1: issue Y reads (Ya 8, Yb 4); lgkmcnt(12) [waits only prior X'];
//          MFMA Q1 (Xa.Xb) while Y drains underneath.
//     ph2: lgkmcnt(4) [Ya ready, Yb in flight]; MFMA Q2 (Ya.Xb).
//     ph3: lgkmcnt(0); vmcnt(0) [tile j+1 stages, 3-4 phases old]; s_barrier;
//          stage tile j+2 A-halves -> cur (WAR-safe: all cur reads returned);
//          read X'b (next tile B-frags); MFMA Q3 (Xa.Yb); read X'a.
//     ph4: stage B-halves; MFMA Q4 (Ya.Yb).
//   lgkm queue per iter: [X'b(4), X'a(8), Y(12)] -> counts 12/4/0 are exact.
//   One barrier/iter is sufficient: adjacent-iter waves touch disjoint
//   buffers (Y' reads other; stages target cur only after the barrier).
//   Epilogue: r4 scalar stores (r5's LDS-transpose epilogue measured -10us).

#define D_MODEL 2048
#define D_STATE 64
#define D_HEAD 128
#define CHUNK 256
#define D_INNER 4096
#define NHEADS 32
#define CONV_DIM 4224
#define D_IN_PROJ 8352
#define NPAD 8448
#define BATCH 2
#define SEQLEN 4096
#define NC 16
#define ROWS 8192
#define EPS_F 1e-5f

typedef unsigned short u16;
typedef __attribute__((ext_vector_type(8))) short bf16x8;
typedef __attribute__((ext_vector_type(4))) float f32x4;

__device__ __forceinline__ float bf2f(u16 u) { return __uint_as_float(((unsigned)u) << 16); }
__device__ __forceinline__ u16 f2bf(float f) {
  unsigned x = __float_as_uint(f);
  x += 0x7FFFu + ((x >> 16) & 1u);
  return (u16)(x >> 16);
}

// ---------------- dtype detection ----------------
__global__ void detect_k(const u16* __restrict__ win, int* __restrict__ flag) {
  __shared__ int cnt;
  if (threadIdx.x == 0) cnt = 0;
  __syncthreads();
  int c = 0;
  for (int i = threadIdx.x; i < 8192; i += 256) {
    u16 x = win[i];
    int e = (x >> 7) & 0xFF;
    if (e != 0 && (e < 90 || e > 160)) c++;
  }
  atomicAdd(&cnt, c);
  __syncthreads();
  if (threadIdx.x == 0) *flag = (cnt > 512) ? 1 : 0;
}

// ---------------- convert small params to fp32 ws arrays ----------------
__device__ __forceinline__ float readin(const void* p, int i, int isf32) {
  return isf32 ? ((const float*)p)[i] : bf2f(((const u16*)p)[i]);
}
#define N_CW 16896
#define N_CB 4224
#define N_SMALL (N_CW + N_CB + 32 + 32 + 32 + 4096)
__global__ __launch_bounds__(256) void convert_small_k(const void* cw, const void* cb,
                                                       const void* dtb, const void* alog,
                                                       const void* Dv, const void* nw,
                                                       const int* __restrict__ flag,
                                                       float* __restrict__ dst) {
  int idx = blockIdx.x * 256 + threadIdx.x;
  if (idx >= N_SMALL) return;
  int f = *flag;
  float v; int o = idx;
  if (o < N_CW) { v = readin(cw, o, f); }
  else if ((o -= N_CW) < N_CB) { v = readin(cb, o, f); }
  else if ((o -= N_CB) < 32) { v = readin(dtb, o, f); }
  else if ((o -= 32) < 32) { v = readin(alog, o, f); }
  else if ((o -= 32) < 32) { v = readin(Dv, o, f); }
  else { o -= 32; v = readin(nw, o, f); }
  dst[idx] = v;
}

// ---------------- convert big tensor -> packed bf16 (zero-pad tail) ----------------
__global__ __launch_bounds__(256) void to_bf16_k(const void* __restrict__ src,
                                                 u16* __restrict__ dst,
                                                 long n_src, long n_total,
                                                 const int* __restrict__ flag) {
  long i = ((long)blockIdx.x * 256 + threadIdx.x) * 8;
  if (i >= n_total) return;
  ushort4 o0, o1;
  if (i >= n_src) {
    o0.x = o0.y = o0.z = o0.w = 0; o1 = o0;
  } else if (*flag) {
    float4 a = *((const float4*)src + (i >> 2));
    float4 b = *((const float4*)src + (i >> 2) + 1);
    o0.x = f2bf(a.x); o0.y = f2bf(a.y); o0.z = f2bf(a.z); o0.w = f2bf(a.w);
    o1.x = f2bf(b.x); o1.y = f2bf(b.y); o1.z = f2bf(b.z); o1.w = f2bf(b.w);
  } else {
    o0 = *((const ushort4*)src + (i >> 2));
    o1 = *((const ushort4*)src + (i >> 2) + 1);
  }
  *(ushort4*)(dst + i) = o0;
  *(ushort4*)(dst + i + 4) = o1;
}

// ---------------- 256x256 MFMA GEMM (v6 frag-ahead) ----------------
__device__ __forceinline__ void glds16(const u16* g, u16* l) {
  __builtin_amdgcn_global_load_lds((const __attribute__((address_space(1))) void*)g,
                                   (__attribute__((address_space(3))) void*)l, 16, 0, 0);
}

template <int OUTDYN>
__global__ __launch_bounds__(512, 2) void gemm256(const u16* __restrict__ A, int lda,
                                                  const u16* __restrict__ B, int ldb,
                                                  void* __restrict__ Cv, int ldc,
                                                  int M, int N, int K,
                                                  const int* __restrict__ flagp) {
  __shared__ __align__(16) u16 As[32768];   // 2 buf x [256 rows x 64 cols]
  __shared__ __align__(16) u16 Bs[32768];
  const int tid = threadIdx.x;
  const int lane = tid & 63, w = tid >> 6;
  const int wm = w >> 2, wn = w & 3;        // wave -> 128x64 output sub-tile

  const int gx = (int)gridDim.x;
  const int nwg = gx * (int)gridDim.y;
  const int phys = (int)blockIdx.y * gx + (int)blockIdx.x;
  const int logical = (phys & 7) * (nwg >> 3) + (phys >> 3);
  const int bm = (logical / gx) << 8;
  const int bn = (logical % gx) << 8;

  const int nk = K >> 6;        // K-tiles of 64
  const int smax = nk << 2;     // half-tile stream: s = 4*kt + {A.h0,A.h1,B.h0,B.h1}

  const int srow = tid >> 3;
  const int scol = ((tid & 7) ^ (srow & 7)) << 3;   // inverse-swizzled source col
  const u16* agb = A + (size_t)(bm + srow) * lda + scol;
  const u16* bgb = B + (size_t)(bn + srow) * ldb + scol;
  const size_t a64 = (size_t)64 * lda, b64 = (size_t)64 * ldb;
  u16* asl = As + tid * 8;
  u16* bsl = Bs + tid * 8;

#define STAGE(sv) do { int s_ = (sv); if (s_ < smax) {                        \
    int kt_ = s_ >> 2, it_ = s_ & 3;                                          \
    int ko_ = kt_ << 6; int dbo_ = (kt_ & 1) << 14;                           \
    if (it_ < 2) {                                                            \
      const u16* g_ = agb + (size_t)(it_ << 7) * lda + ko_;                   \
      u16* l_ = asl + dbo_ + (it_ << 13);                                     \
      glds16(g_, l_); glds16(g_ + a64, l_ + 4096);                            \
    } else {                                                                  \
      const u16* g_ = bgb + (size_t)((it_ & 1) << 7) * ldb + ko_;             \
      u16* l_ = bsl + dbo_ + ((it_ & 1) << 13);                               \
      glds16(g_, l_); glds16(g_ + b64, l_ + 4096);                            \
    } } } while (0)

  f32x4 acc[8][4];
  #pragma unroll
  for (int i = 0; i < 8; ++i)
    #pragma unroll
    for (int n = 0; n < 4; ++n) { acc[i][n].x = 0.f; acc[i][n].y = 0.f; acc[i][n].z = 0.f; acc[i][n].w = 0.f; }

  // prologue: stage tiles 0,1 fully; wait tile 0; pre-read X frags of tile 0
  STAGE(0); STAGE(1); STAGE(2); STAGE(3);
  STAGE(4); STAGE(5); STAGE(6); STAGE(7);
  asm volatile("s_waitcnt vmcnt(8)" ::: "memory");
  __builtin_amdgcn_s_barrier();
  __builtin_amdgcn_sched_barrier(0);

  const int m16 = lane & 15;
  const int rsw = (lane & 7) << 3;
  const int c0 = (((lane >> 4) << 3)) ^ rsw;
  const int c1 = (32 | ((lane >> 4) << 3)) ^ rsw;
  const int aRow = (((wm << 7) + m16) << 6);
  const int bRow = (((wn << 6) + m16) << 6);

  bf16x8 af[8][2], bfv[4][2];

  // pre-read X of tile 0 (Xb first, then Xa — matches steady-state queue order)
  {
    const u16* Ab = As + aRow;
    const u16* Bb = Bs + bRow;
    #pragma unroll
    for (int n = 0; n < 2; ++n) {
      bfv[n][0] = *(const bf16x8*)(Bb + n * 1024 + c0);
      bfv[n][1] = *(const bf16x8*)(Bb + n * 1024 + c1);
    }
    #pragma unroll
    for (int i = 0; i < 4; ++i) {
      af[i][0] = *(const bf16x8*)(Ab + i * 1024 + c0);
      af[i][1] = *(const bf16x8*)(Ab + i * 1024 + c1);
    }
  }

  for (int j = 0; j < nk; ++j) {
    const int db = (j & 1) << 14;
    const int dbo = db ^ 16384;
    const u16* Ab = As + db + aRow;
    const u16* Bb = Bs + db + bRow;
    const u16* Abo = As + dbo + aRow;
    const u16* Bbo = Bs + dbo + bRow;

    // ---- ph1: issue Y reads; wait prior X'; MFMA Q1 (Xa.Xb) ----
    #pragma unroll
    for (int i = 4; i < 8; ++i) {               // Ya (8 reads)
      af[i][0] = *(const bf16x8*)(Ab + i * 1024 + c0);
      af[i][1] = *(const bf16x8*)(Ab + i * 1024 + c1);
    }
    #pragma unroll
    for (int n = 2; n < 4; ++n) {               // Yb (4 reads)
      bfv[n][0] = *(const bf16x8*)(Bb + n * 1024 + c0);
      bfv[n][1] = *(const bf16x8*)(Bb + n * 1024 + c1);
    }
    __builtin_amdgcn_sched_barrier(0);
    asm volatile("s_waitcnt lgkmcnt(12)" ::: "memory");   // X' returned; Y in flight
    __builtin_amdgcn_sched_barrier(0);
    __builtin_amdgcn_s_setprio(1);
    #pragma unroll
    for (int k = 0; k < 2; ++k)
      #pragma unroll
      for (int i = 0; i < 4; ++i)
        #pragma unroll
        for (int n = 0; n < 2; ++n)
          acc[i][n] = __builtin_amdgcn_mfma_f32_16x16x32_bf16(af[i][k], bfv[n][k], acc[i][n], 0, 0, 0);
    __builtin_amdgcn_s_setprio(0);
    __builtin_amdgcn_sched_barrier(0);

    // ---- ph2: wait Ya; MFMA Q2 (Ya.Xb) ----
    asm volatile("s_waitcnt lgkmcnt(4)" ::: "memory");    // Ya returned; Yb in flight
    __builtin_amdgcn_sched_barrier(0);
    __builtin_amdgcn_s_setprio(1);
    #pragma unroll
    for (int k = 0; k < 2; ++k)
      #pragma unroll
      for (int i = 4; i < 8; ++i)
        #pragma unroll
        for (int n = 0; n < 2; ++n)
          acc[i][n] = __builtin_amdgcn_mfma_f32_16x16x32_bf16(af[i][k], bfv[n][k], acc[i][n], 0, 0, 0);
    __builtin_amdgcn_s_setprio(0);
    __builtin_amdgcn_sched_barrier(0);

    // ---- ph3: full drain; ONE barrier; stage A(j+2)->cur; X'b; Q3; X'a ----
    asm volatile("s_waitcnt lgkmcnt(0) vmcnt(0)" ::: "memory");
    __builtin_amdgcn_sched_barrier(0);
    __builtin_amdgcn_s_barrier();
    __builtin_amdgcn_sched_barrier(0);
    STAGE(((j + 2) << 2) + 0);
    STAGE(((j + 2) << 2) + 1);
    if (j + 1 < nk) {
      #pragma unroll
      for (int n = 0; n < 2; ++n) {             // X'b (4 reads, other buffer)
        bfv[n][0] = *(const bf16x8*)(Bbo + n * 1024 + c0);
        bfv[n][1] = *(const bf16x8*)(Bbo + n * 1024 + c1);
      }
    }
    __builtin_amdgcn_sched_barrier(0);
    __builtin_amdgcn_s_setprio(1);
    #pragma unroll
    for (int k = 0; k < 2; ++k)
      #pragma unroll
      for (int i = 0; i < 4; ++i)
        #pragma unroll
        for (int n = 2; n < 4; ++n)
          acc[i][n] = __builtin_amdgcn_mfma_f32_16x16x32_bf16(af[i][k], bfv[n][k], acc[i][n], 0, 0, 0);
    __builtin_amdgcn_s_setprio(0);
    if (j + 1 < nk) {
      #pragma unroll
      for (int i = 0; i < 4; ++i) {             // X'a (8 reads, other buffer)
        af[i][0] = *(const bf16x8*)(Abo + i * 1024 + c0);
        af[i][1] = *(const bf16x8*)(Abo + i * 1024 + c1);
      }
    }
    __builtin_amdgcn_sched_barrier(0);

    // ---- ph4: stage B(j+2)->cur; MFMA Q4 (Ya.Yb) ----
    STAGE(((j + 2) << 2) + 2);
    STAGE(((j + 2) << 2) + 3);
    __builtin_amdgcn_sched_barrier(0);
    __builtin_amdgcn_s_setprio(1);
    #pragma unroll
    for (int k = 0; k < 2; ++k)
      #pragma unroll
      for (int i = 4; i < 8; ++i)
        #pragma unroll
        for (int n = 2; n < 4; ++n)
          acc[i][n] = __builtin_amdgcn_mfma_f32_16x16x32_bf16(af[i][k], bfv[n][k], acc[i][n], 0, 0, 0);
    __builtin_amdgcn_s_setprio(0);
    __builtin_amdgcn_sched_barrier(0);
  }
#undef STAGE

  // ---- epilogue (r4 scalar stores) ----
  const int r4 = (lane >> 4) << 2;
  int f = 0;
  if (OUTDYN) f = *flagp;
  #pragma unroll
  for (int i = 0; i < 8; ++i) {
    #pragma unroll
    for (int r = 0; r < 4; ++r) {
      size_t rowoff = (size_t)(bm + (wm << 7) + i * 16 + r4 + r) * ldc;
      #pragma unroll
      for (int n = 0; n < 4; ++n) {
        int col = bn + (wn << 6) + n * 16 + m16;
        if (col < N) {
          float v = acc[i][n][r];
          if (OUTDYN && f) ((float*)Cv)[rowoff + col] = v;
          else             ((u16*)Cv)[rowoff + col] = f2bf(v);
        }
      }
    }
  }
}

// ---------------- causal conv4 + SiLU (vectorized x8) ----------------
__global__ __launch_bounds__(256) void conv_silu_k(const u16* __restrict__ zx,
                                                   const float* __restrict__ cwf,
                                                   const float* __restrict__ cbf,
                                                   u16* __restrict__ xBC) {
  int idx = blockIdx.x * 256 + threadIdx.x;   // 0..527
  if (idx >= (CONV_DIM / 8)) return;
  int c0 = idx << 3;
  int row = blockIdx.y;
  int b = row >> 12, l = row & 4095;
  float acc[8];
  #pragma unroll
  for (int j = 0; j < 8; ++j) acc[j] = cbf[c0 + j];
  #pragma unroll
  for (int k = 0; k < 4; ++k) {
    int li = l - 3 + k;
    if (li >= 0) {
      const u16* zp = zx + (size_t)(b * SEQLEN + li) * D_IN_PROJ + D_INNER + c0;
      ushort4 v0 = *(const ushort4*)zp;
      ushort4 v1 = *(const ushort4*)(zp + 4);
      float xv[8] = {bf2f(v0.x), bf2f(v0.y), bf2f(v0.z), bf2f(v0.w),
                     bf2f(v1.x), bf2f(v1.y), bf2f(v1.z), bf2f(v1.w)};
      #pragma unroll
      for (int j = 0; j < 8; ++j) acc[j] += xv[j] * cwf[(c0 + j) * 4 + k];
    }
  }
  ushort4 o0, o1;
  float a0 = acc[0] / (1.f + __expf(-acc[0])); o0.x = f2bf(a0);
  float a1 = acc[1] / (1.f + __expf(-acc[1])); o0.y = f2bf(a1);
  float a2 = acc[2] / (1.f + __expf(-acc[2])); o0.z = f2bf(a2);
  float a3 = acc[3] / (1.f + __expf(-acc[3])); o0.w = f2bf(a3);
  float a4 = acc[4] / (1.f + __expf(-acc[4])); o1.x = f2bf(a4);
  float a5 = acc[5] / (1.f + __expf(-acc[5])); o1.y = f2bf(a5);
  float a6 = acc[6] / (1.f + __expf(-acc[6])); o1.z = f2bf(a6);
  float a7 = acc[7] / (1.f + __expf(-acc[7])); o1.w = f2bf(a7);
  u16* dst = xBC + (size_t)row * CONV_DIM + c0;
  *(ushort4*)dst = o0;
  *(ushort4*)(dst + 4) = o1;
}

// ---------------- dt = softplus(raw + bias) ----------------
__global__ __launch_bounds__(256) void dt_softplus_k(const u16* __restrict__ zx,
                                                     const float* __restrict__ dtbf,
                                                     float* __restrict__ dtf) {
  int idx = blockIdx.x * 256 + threadIdx.x;   // ROWS*NHEADS
  int i = idx >> 5, h = idx & 31;
  float x = bf2f(zx[(size_t)i * D_IN_PROJ + (D_INNER + CONV_DIM) + h]) + dtbf[h];
  float sp = (x > 20.f) ? x : log1pf(__expf(fminf(x, 20.f)));
  dtf[idx] = sp;
}

// ---------------- per-chunk cum, decay, states ----------------
__global__ __launch_bounds__(256) void chunk_states_k(const u16* __restrict__ xBC,
                                                      const float* __restrict__ dtf,
                                                      const float* __restrict__ alogf,
                                                      float* __restrict__ cumf,
                                                      float* __restrict__ cdec,
                                                      float* __restrict__ states) {
  const int h = blockIdx.x, c = blockIdx.y, b = blockIdx.z;
  const int tid = threadIdx.x;
  __shared__ __align__(16) float dt_sh[CHUNK];
  __shared__ __align__(16) float cum_sh[CHUNK];
  __shared__ __align__(16) float w_sh[CHUNK];
  __shared__ __align__(16) float xs[64][132];
  __shared__ __align__(16) float Bst[64][68];
  const int rowbase = b * SEQLEN + c * CHUNK;
  dt_sh[tid] = dtf[(size_t)(rowbase + tid) * NHEADS + h];
  __syncthreads();
  if (tid == 0) {
    float Aneg = -__expf(alogf[h]);
    float s = 0.f;
    for (int z = 0; z < CHUNK; ++z) { s += dt_sh[z] * Aneg; cum_sh[z] = s; }
  }
  __syncthreads();
  float cl = cum_sh[CHUNK - 1];
  w_sh[tid] = __expf(fminf(cl - cum_sh[tid], 0.f)) * dt_sh[tid];
  cumf[((size_t)(b * NC + c) * NHEADS + h) * CHUNK + tid] = cum_sh[tid];
  if (tid == 0) cdec[(b * NC + c) * NHEADS + h] = __expf(fminf(cl, 0.f));
  __syncthreads();
  const int tx = tid & 15, ty = tid >> 4;
  const int p0 = tx << 3, n0 = ty << 2;
  float acc[8][4];
  #pragma unroll
  for (int i = 0; i < 8; ++i)
    #pragma unroll
    for (int j = 0; j < 4; ++j) acc[i][j] = 0.f;
  for (int z0 = 0; z0 < CHUNK; z0 += 64) {
    int zz = tid >> 2;
    int pq = (tid & 3) << 5;
    const u16* xp = xBC + (size_t)(rowbase + z0 + zz) * CONV_DIM + h * D_HEAD + pq;
    #pragma unroll
    for (int q = 0; q < 8; ++q) {
      ushort4 v = *(const ushort4*)(xp + q * 4);
      xs[zz][pq + q*4 + 0] = bf2f(v.x); xs[zz][pq + q*4 + 1] = bf2f(v.y);
      xs[zz][pq + q*4 + 2] = bf2f(v.z); xs[zz][pq + q*4 + 3] = bf2f(v.w);
    }
    int nq = (tid & 3) << 4;
    const u16* bpp = xBC + (size_t)(rowbase + z0 + zz) * CONV_DIM + D_INNER + nq;
    float wz = w_sh[z0 + zz];
    #pragma unroll
    for (int q = 0; q < 4; ++q) {
      ushort4 v = *(const ushort4*)(bpp + q * 4);
      Bst[zz][nq + q*4 + 0] = bf2f(v.x) * wz; Bst[zz][nq + q*4 + 1] = bf2f(v.y) * wz;
      Bst[zz][nq + q*4 + 2] = bf2f(v.z) * wz; Bst[zz][nq + q*4 + 3] = bf2f(v.w) * wz;
    }
    __syncthreads();
    #pragma unroll 4
    for (int z = 0; z < 64; ++z) {
      float4 x0 = *(const float4*)&xs[z][p0];
      float4 x1 = *(const float4*)&xs[z][p0 + 4];
      float4 bv = *(const float4*)&Bst[z][n0];
      float xv[8] = {x0.x, x0.y, x0.z, x0.w, x1.x, x1.y, x1.z, x1.w};
      float bb[4] = {bv.x, bv.y, bv.z, bv.w};
      #pragma unroll
      for (int i = 0; i < 8; ++i)
        #pragma unroll
        for (int j = 0; j < 4; ++j) acc[i][j] += xv[i] * bb[j];
    }
    __syncthreads();
  }
  float* sp = states + ((size_t)(b * NC + c) * NHEADS + h) * (D_HEAD * D_STATE);
  #pragma unroll
  for (int i = 0; i < 8; ++i)
    #pragma unroll
    for (int j = 0; j < 4; ++j)
      sp[(size_t)(p0 + i) * D_STATE + n0 + j] = acc[i][j];
}

// ---------------- inter-chunk scan (IN-PLACE, 512 blocks) ----------------
__global__ __launch_bounds__(256) void scan_k(float* __restrict__ states,
                                              const float* __restrict__ cdec) {
  const int g = blockIdx.x, h = blockIdx.y, b = blockIdx.z;
  const int tid = threadIdx.x;
  const int e0 = (g << 10) + tid;
  float carry[4];
  #pragma unroll
  for (int j = 0; j < 4; ++j) carry[j] = 0.f;
  for (int c = 0; c < NC; ++c) {
    size_t base = ((size_t)(b * NC + c) * NHEADS + h) * (D_HEAD * D_STATE);
    float dec = cdec[(b * NC + c) * NHEADS + h];
    #pragma unroll
    for (int j = 0; j < 4; ++j) {
      size_t e = base + e0 + (j << 8);
      float s = states[e];
      states[e] = carry[j];
      carry[j] = carry[j] * dec + s;
    }
  }
}

// ---------------- scores = C . B^T ----------------
__global__ __launch_bounds__(256) void scores_k(const u16* __restrict__ xBC,
                                                float* __restrict__ scores) {
  const int bx = blockIdx.x;            // 0..15
  const int c = blockIdx.y, b = blockIdx.z;
  const int s0 = (bx >> 2) << 6, z0 = (bx & 3) << 6;
  __shared__ __align__(16) float Cs[64][68];   // [n][s]
  __shared__ __align__(16) float Bs2[64][68];  // [n][z]
  const int tid = threadIdx.x;
  const int rowbase = b * SEQLEN + c * CHUNK;
  int r = tid >> 2, nq = (tid & 3) << 4;
  const u16* cp = xBC + (size_t)(rowbase + s0 + r) * CONV_DIM + D_INNER + D_STATE + nq;
  const u16* bp = xBC + (size_t)(rowbase + z0 + r) * CONV_DIM + D_INNER + nq;
  #pragma unroll
  for (int q = 0; q < 16; q += 4) {
    ushort4 v = *(const ushort4*)(cp + q);
    Cs[nq+q+0][r] = bf2f(v.x); Cs[nq+q+1][r] = bf2f(v.y);
    Cs[nq+q+2][r] = bf2f(v.z); Cs[nq+q+3][r] = bf2f(v.w);
    ushort4 w2 = *(const ushort4*)(bp + q);
    Bs2[nq+q+0][r] = bf2f(w2.x); Bs2[nq+q+1][r] = bf2f(w2.y);
    Bs2[nq+q+2][r] = bf2f(w2.z); Bs2[nq+q+3][r] = bf2f(w2.w);
  }
  __syncthreads();
  const int tx = tid & 15, ty = tid >> 4;
  float acc[4][4];
  #pragma unroll
  for (int i = 0; i < 4; ++i)
    #pragma unroll
    for (int j = 0; j < 4; ++j) acc[i][j] = 0.f;
  #pragma unroll 8
  for (int n = 0; n < 64; ++n) {
    float4 a = *(const float4*)&Cs[n][ty << 2];
    float4 bb = *(const float4*)&Bs2[n][tx << 2];
    float av[4] = {a.x, a.y, a.z, a.w};
    float bv[4] = {bb.x, bb.y, bb.z, bb.w};
    #pragma unroll
    for (int i = 0; i < 4; ++i)
      #pragma unroll
      for (int j = 0; j < 4; ++j) acc[i][j] += av[i] * bv[j];
  }
  float* spp = scores + (size_t)(b * NC + c) * CHUNK * CHUNK;
  #pragma unroll
  for (int i = 0; i < 4; ++i)
    #pragma unroll
    for (int j = 0; j < 4; ++j)
      spp[(size_t)(s0 + (ty << 2) + i) * CHUNK + z0 + (tx << 2) + j] = acc[i][j];
}

// ---------------- Y via MFMA: (scores*L*dt)@x^T + exp(cum)*C@prev^T + D*x ----------------
__global__ __launch_bounds__(256) void ydiag_mfma_k(const u16* __restrict__ xBC,
                                                    const float* __restrict__ dtf,
                                                    const float* __restrict__ cumf,
                                                    const float* __restrict__ scores,
                                                    const float* __restrict__ prevst,
                                                    const float* __restrict__ df,
                                                    u16* __restrict__ y) {
  const int h = blockIdx.x, c = blockIdx.y, b = blockIdx.z;
  const int tid = threadIdx.x;
  const int lane = tid & 63, w = tid >> 6;
  const int wm = w >> 1, wn = w & 1;          // wave -> 128x64 of 256x128 out
  __shared__ __align__(16) u16 Pl[256 * 64];  // A-tile [s][64], swizzled slots
  __shared__ __align__(16) u16 Xl[128 * 64];  // B-tile [p][64], swizzled slots
  __shared__ __align__(16) float cum_sh[CHUNK];
  __shared__ __align__(16) float dts[CHUNK];
  const int rowbase = b * SEQLEN + c * CHUNK;
  const int hoff = h * D_HEAD;
  cum_sh[tid] = cumf[((size_t)(b * NC + c) * NHEADS + h) * CHUNK + tid];
  dts[tid] = dtf[(size_t)(rowbase + tid) * NHEADS + h];
  const float* scb = scores + (size_t)(b * NC + c) * CHUNK * CHUNK;
  const float* prevb = prevst + ((size_t)(b * NC + c) * NHEADS + h) * (D_HEAD * D_STATE);

  f32x4 acc[8][4];
  #pragma unroll
  for (int i = 0; i < 8; ++i)
    #pragma unroll
    for (int n = 0; n < 4; ++n) { acc[i][n].x = 0.f; acc[i][n].y = 0.f; acc[i][n].z = 0.f; acc[i][n].w = 0.f; }

  const int m16 = lane & 15;
  const int rsw = (lane & 7) << 3;
  const int c0 = (((lane >> 4) << 3)) ^ rsw;
  const int c1 = (32 | ((lane >> 4) << 3)) ^ rsw;

  for (int step = 0; step < 5; ++step) {
    __syncthreads();
    if (step < 4) {
      const int z0 = step << 6;
      // ---- P~ staging: 8 coalesced row-passes (8 lanes per row) ----
      {
        const int sr = tid >> 3;            // 0..31
        const int zq = (tid & 7) << 3;      // col group
        #pragma unroll
        for (int pp = 0; pp < 8; ++pp) {
          int s = (pp << 5) + sr;
          float cs = cum_sh[s];
          const float* srow = scb + (size_t)s * CHUNK + z0 + zq;
          float4 fa = *(const float4*)srow;
          float4 fb = *(const float4*)(srow + 4);
          float fv[8] = {fa.x, fa.y, fa.z, fa.w, fb.x, fb.y, fb.z, fb.w};
          u16 e[8];
          #pragma unroll
          for (int i2 = 0; i2 < 8; ++i2) {
            int z = z0 + zq + i2;
            float val = (z <= s) ? fv[i2] * __expf(fminf(cs - cum_sh[z], 0.f)) * dts[z] : 0.f;
            e[i2] = f2bf(val);
          }
          ushort4 lo, hi;
          lo.x = e[0]; lo.y = e[1]; lo.z = e[2]; lo.w = e[3];
          hi.x = e[4]; hi.y = e[5]; hi.z = e[6]; hi.w = e[7];
          u16* dst = Pl + (s << 6) + ((((zq >> 3) ^ (s & 7))) << 3);
          *(ushort4*)dst = lo; *(ushort4*)(dst + 4) = hi;
        }
      }
      // ---- Xt staging: coalesced 16B reads of x[z][p], LDS scatter transpose ----
      {
        const int zz = tid >> 2;            // 0..63 (z within tile)
        const int ps = (tid & 3) << 5;      // p group of 32
        const u16* xg = xBC + (size_t)(rowbase + z0 + zz) * CONV_DIM + hoff + ps;
        bf16x8 va = *(const bf16x8*)xg;
        bf16x8 vb = *(const bf16x8*)(xg + 8);
        bf16x8 vc = *(const bf16x8*)(xg + 16);
        bf16x8 vd = *(const bf16x8*)(xg + 24);
        const int zhi = (zz >> 3), zlo = zz & 7;
        #pragma unroll
        for (int q = 0; q < 4; ++q) {
          #pragma unroll
          for (int i2 = 0; i2 < 8; ++i2) {
            u16 val = (u16)(q == 0 ? va[i2] : q == 1 ? vb[i2] : q == 2 ? vc[i2] : vd[i2]);
            int p = ps + (q << 3) + i2;
            Xl[(p << 6) + ((zhi ^ (p & 7)) << 3) + zlo] = val;
          }
        }
      }
    } else {
      // ---- off staging: A2[s][n] = exp(cum[s])*C[s,n] (coalesced row-passes) ----
      {
        const int sr = tid >> 3;
        const int nq = (tid & 7) << 3;
        #pragma unroll
        for (int pp = 0; pp < 8; ++pp) {
          int s = (pp << 5) + sr;
          float es = __expf(fminf(cum_sh[s], 0.f));
          const u16* crow = xBC + (size_t)(rowbase + s) * CONV_DIM + D_INNER + D_STATE + nq;
          ushort4 a = *(const ushort4*)crow;
          ushort4 b4 = *(const ushort4*)(crow + 4);
          ushort4 lo, hi;
          lo.x = f2bf(bf2f(a.x) * es); lo.y = f2bf(bf2f(a.y) * es);
          lo.z = f2bf(bf2f(a.z) * es); lo.w = f2bf(bf2f(a.w) * es);
          hi.x = f2bf(bf2f(b4.x) * es); hi.y = f2bf(bf2f(b4.y) * es);
          hi.z = f2bf(bf2f(b4.z) * es); hi.w = f2bf(bf2f(b4.w) * es);
          u16* dst = Pl + (s << 6) + ((((nq >> 3) ^ (s & 7))) << 3);
          *(ushort4*)dst = lo; *(ushort4*)(dst + 4) = hi;
        }
      }
      // ---- B2[p][n] = prev[p,n] (natural layout, row-coalesced) ----
      {
        const int p = tid >> 1;
        const float* pr = prevb + (size_t)p * D_STATE;
        u16* xrow = Xl + (p << 6);
        #pragma unroll
        for (int kk = 0; kk < 4; ++kk) {
          int q = ((tid & 1) << 2) + kk;
          float4 f0 = *(const float4*)(pr + (q << 3));
          float4 f1 = *(const float4*)(pr + (q << 3) + 4);
          ushort4 lo, hi;
          lo.x = f2bf(f0.x); lo.y = f2bf(f0.y); lo.z = f2bf(f0.z); lo.w = f2bf(f0.w);
          hi.x = f2bf(f1.x); hi.y = f2bf(f1.y); hi.z = f2bf(f1.z); hi.w = f2bf(f1.w);
          u16* dst = xrow + ((q ^ (p & 7)) << 3);
          *(ushort4*)dst = lo; *(ushort4*)(dst + 4) = hi;
        }
      }
    }
    __syncthreads();
    // ---- fragments + MFMA ----
    bf16x8 af[8][2], bfv[4][2];
    #pragma unroll
    for (int i = 0; i < 8; ++i) {
      const u16* base = Pl + ((((wm << 7) + (i << 4) + m16)) << 6);
      af[i][0] = *(const bf16x8*)(base + c0);
      af[i][1] = *(const bf16x8*)(base + c1);
    }
    #pragma unroll
    for (int n = 0; n < 4; ++n) {
      const u16* base = Xl + ((((wn << 6) + (n << 4) + m16)) << 6);
      bfv[n][0] = *(const bf16x8*)(base + c0);
      bfv[n][1] = *(const bf16x8*)(base + c1);
    }
    #pragma unroll
    for (int k = 0; k < 2; ++k)
      #pragma unroll
      for (int i = 0; i < 8; ++i)
        #pragma unroll
        for (int n = 0; n < 4; ++n)
          acc[i][n] = __builtin_amdgcn_mfma_f32_16x16x32_bf16(af[i][k], bfv[n][k], acc[i][n], 0, 0, 0);
  }

  // epilogue: + D*x, store bf16.  C/D layout: col = lane&15, row = (lane>>4)*4 + reg
  const float Dvv = df[h];
  const int r4 = (lane >> 4) << 2;
  #pragma unroll
  for (int i = 0; i < 8; ++i) {
    #pragma unroll
    for (int r = 0; r < 4; ++r) {
      int srow2 = (wm << 7) + (i << 4) + r4 + r;
      size_t grow = (size_t)(rowbase + srow2);
      #pragma unroll
      for (int n = 0; n < 4; ++n) {
        int p = (wn << 6) + (n << 4) + m16;
        float v = acc[i][n][r] + bf2f(xBC[grow * CONV_DIM + hoff + p]) * Dvv;
        y[grow * D_IN_PROJ + D_INNER + hoff + p] = f2bf(v);
      }
    }
  }
}

// ---------------- gating + RMSNorm (vectorized x8, in-place) ----------------
__global__ __launch_bounds__(256) void gatenorm_k(u16* __restrict__ zx,
                                                  const float* __restrict__ nwf) {
  const int row = blockIdx.x;
  const int tid = threadIdx.x;
  u16* zrow = zx + (size_t)row * D_IN_PROJ;
  u16* yrow = zrow + D_INNER;
  float vals[16];
  float ss = 0.f;
  #pragma unroll
  for (int q = 0; q < 2; ++q) {
    int e8 = (tid + (q << 8)) << 3;
    ushort4 y0 = *(const ushort4*)(yrow + e8);
    ushort4 y1 = *(const ushort4*)(yrow + e8 + 4);
    ushort4 z0 = *(const ushort4*)(zrow + e8);
    ushort4 z1 = *(const ushort4*)(zrow + e8 + 4);
    float yv[8] = {bf2f(y0.x), bf2f(y0.y), bf2f(y0.z), bf2f(y0.w),
                   bf2f(y1.x), bf2f(y1.y), bf2f(y1.z), bf2f(y1.w)};
    float zv[8] = {bf2f(z0.x), bf2f(z0.y), bf2f(z0.z), bf2f(z0.w),
                   bf2f(z1.x), bf2f(z1.y), bf2f(z1.z), bf2f(z1.w)};
    #pragma unroll
    for (int j = 0; j < 8; ++j) {
      float g = yv[j] * (zv[j] / (1.f + __expf(-zv[j])));
      vals[q * 8 + j] = g;
      ss += g * g;
    }
  }
  #pragma unroll
  for (int off = 1; off < 64; off <<= 1) ss += __shfl_xor(ss, off);
  __shared__ float red[4];
  int lane = tid & 63, wv = tid >> 6;
  if (lane == 0) red[wv] = ss;
  __syncthreads();
  float tot = red[0] + red[1] + red[2] + red[3];
  float scale = rsqrtf(tot * (1.f / D_INNER) + EPS_F);
  #pragma unroll
  for (int q = 0; q < 2; ++q) {
    int e8 = (tid + (q << 8)) << 3;
    ushort4 o0, o1;
    o0.x = f2bf(vals[q*8+0] * scale * nwf[e8+0]);
    o0.y = f2bf(vals[q*8+1] * scale * nwf[e8+1]);
    o0.z = f2bf(vals[q*8+2] * scale * nwf[e8+2]);
    o0.w = f2bf(vals[q*8+3] * scale * nwf[e8+3]);
    o1.x = f2bf(vals[q*8+4] * scale * nwf[e8+4]);
    o1.y = f2bf(vals[q*8+5] * scale * nwf[e8+5]);
    o1.z = f2bf(vals[q*8+6] * scale * nwf[e8+6]);
    o1.w = f2bf(vals[q*8+7] * scale * nwf[e8+7]);
    *(ushort4*)(yrow + e8) = o0;
    *(ushort4*)(yrow + e8 + 4) = o1;
  }
}

extern "C" void kernel_launch(void* const* d_in, const int* in_sizes, int n_in,
                              void* d_out, int out_size, void* d_ws, size_t ws_size,
                              hipStream_t stream) {
  (void)in_sizes; (void)n_in; (void)out_size; (void)ws_size;
  const void* u       = d_in[0];
  const void* W_in    = d_in[1];
  const void* conv_w  = d_in[2];
  const void* conv_b  = d_in[3];
  const void* dt_bias = d_in[4];
  const void* A_log   = d_in[5];
  const void* Dv      = d_in[6];
  const void* norm_w  = d_in[7];
  const void* W_out   = d_in[8];

  const long N_U    = (long)ROWS * D_MODEL;
  const long N_WIN  = (long)D_IN_PROJ * D_MODEL;
  const long N_WINP = (long)NPAD * D_MODEL;
  const long N_WOUT = (long)D_MODEL * D_INNER;

  char* w = (char*)d_ws;
  size_t o = 0;
  int*   flag  = (int*)(w + o);    o += 256;
  float* smallp= (float*)(w + o);  o += ((size_t)N_SMALL * 4 + 255) & ~(size_t)255;
  u16* zx      = (u16*)(w + o);    o += (size_t)ROWS * D_IN_PROJ * 2;
  u16* r2      = (u16*)(w + o);    o += (size_t)ROWS * CONV_DIM * 2;
  char* r3     = (char*)(w + o);   o += (size_t)BATCH * NC * NHEADS * D_HEAD * D_STATE * 4;
  float* dtf   = (float*)(w + o);  o += (size_t)ROWS * NHEADS * 4;
  float* cumf  = (float*)(w + o);  o += (size_t)BATCH * NC * NHEADS * CHUNK * 4;
  float* cdec  = (float*)(w + o);  o += ((size_t)BATCH * NC * NHEADS * 4 + 255) & ~(size_t)255;
  float* scores= (float*)(w + o);  o += (size_t)BATCH * NC * CHUNK * CHUNK * 4;

  u16* Win_b  = r2;
  u16* xbc    = r2;
  u16* Wout_b = r2;
  u16* u_b    = (u16*)r3;
  float* states = (float*)r3;

  float* cwf  = smallp;
  float* cbf  = smallp + N_CW;
  float* dtbf = cbf + N_CB;
  float* alogf= dtbf + 32;
  float* df   = alogf + 32;
  float* nwf  = df + 32;

  detect_k<<<1, 256, 0, stream>>>((const u16*)W_in, flag);
  convert_small_k<<<(N_SMALL + 255) / 256, 256, 0, stream>>>(
      conv_w, conv_b, dt_bias, A_log, Dv, norm_w, flag, smallp);
  to_bf16_k<<<(int)((N_U / 8 + 255) / 256), 256, 0, stream>>>(u, u_b, N_U, N_U, flag);
  to_bf16_k<<<(int)((N_WINP / 8 + 255) / 256), 256, 0, stream>>>(W_in, Win_b, N_WIN, N_WINP, flag);

  // 1. in_proj
  gemm256<0><<<dim3(NPAD / 256, ROWS / 256), 512, 0, stream>>>(
      u_b, D_MODEL, Win_b, D_MODEL, zx, D_IN_PROJ, ROWS, D_IN_PROJ, D_MODEL, flag);
  // 2. conv + silu
  conv_silu_k<<<dim3((CONV_DIM / 8 + 255) / 256, ROWS), 256, 0, stream>>>(zx, cwf, cbf, xbc);
  // 3. dt softplus
  dt_softplus_k<<<dim3(ROWS * NHEADS / 256), 256, 0, stream>>>(zx, dtbf, dtf);
  // 4. chunk states
  chunk_states_k<<<dim3(NHEADS, NC, BATCH), 256, 0, stream>>>(xbc, dtf, alogf, cumf, cdec, states);
  // 5. scan
  scan_k<<<dim3(8, NHEADS, BATCH), 256, 0, stream>>>(states, cdec);
  // 6. scores
  scores_k<<<dim3(16, NC, BATCH), 256, 0, stream>>>(xbc, scores);
  // 7. Y via MFMA
  ydiag_mfma_k<<<dim3(NHEADS, NC, BATCH), 256, 0, stream>>>(
      xbc, dtf, cumf, scores, states, df, zx);
  // 7.5 convert W_out
  to_bf16_k<<<(int)((N_WOUT / 8 + 255) / 256), 256, 0, stream>>>(W_out, Wout_b, N_WOUT, N_WOUT, flag);
  // 8. gate + norm
  gatenorm_k<<<dim3(ROWS), 256, 0, stream>>>(zx, nwf);
  // 9. out_proj
  gemm256<1><<<dim3(D_MODEL / 256, ROWS / 256), 512, 0, stream>>>(
      zx + D_INNER, D_IN_PROJ, Wout_b, D_INNER, d_out, D_MODEL, ROWS, D_MODEL, D_INNER, flag);
}

// Round 7
// 1070.773 us; speedup vs baseline: 1.0978x; 1.0978x over previous
//
#include <hip/hip_runtime.h>
#include <cstddef>

// Mamba2 forward, MI355X. bf16 MFMA GEMMs + MFMA ydiag + MFMA chunk_states.
//  0 detect_k / convert_small_k / to_bf16_k(u, W_in)
//  1 gemm256        : zxbcdt = u_b @ Win_b^T    (r4-LOCKED schedule: r2 K-loop,
//                     scalar epilogue — 330/165us, MfmaUtil 37, conflicts 0;
//                     r3/r5/r6 restructurings all measured neutral-to-negative)
//  2 conv_silu_k    : causal conv4 + SiLU       (ushort8-vectorized)
//  3 dt_softplus_k  : dt = softplus(raw + dt_bias)
//  4 chunk_states_k : NOW MFMA + wave-parallel cumsum (was: serial tid0 scan
//                     [256 dependent LDS RMW ~15us/block] + fp32 VALU GEMM)
//  5 scan_k         : inter-chunk scan, NOW software-pipelined (prefetch c+1
//                     before the carry update; cdec preloaded) — was a 16-deep
//                     dependent HBM RMW chain
//  6 scores_k       : scores = C.B^T per (b,chunk)
//  7 ydiag_mfma_k   : Y = (scores*L*dt)@x^T + exp(cum)*C@prev^T + D*x  [MFMA]
//  7.5 to_bf16_k(W_out)
//  8 gatenorm_k     : yg = y*silu(z); RMSNorm   (ushort8-vectorized)
//  9 gemm256        : out = yn @ Wout_b^T

#define D_MODEL 2048
#define D_STATE 64
#define D_HEAD 128
#define CHUNK 256
#define D_INNER 4096
#define NHEADS 32
#define CONV_DIM 4224
#define D_IN_PROJ 8352
#define NPAD 8448
#define BATCH 2
#define SEQLEN 4096
#define NC 16
#define ROWS 8192
#define EPS_F 1e-5f

typedef unsigned short u16;
typedef __attribute__((ext_vector_type(8))) short bf16x8;
typedef __attribute__((ext_vector_type(4))) float f32x4;

__device__ __forceinline__ float bf2f(u16 u) { return __uint_as_float(((unsigned)u) << 16); }
__device__ __forceinline__ u16 f2bf(float f) {
  unsigned x = __float_as_uint(f);
  x += 0x7FFFu + ((x >> 16) & 1u);
  return (u16)(x >> 16);
}

// ---------------- dtype detection ----------------
__global__ void detect_k(const u16* __restrict__ win, int* __restrict__ flag) {
  __shared__ int cnt;
  if (threadIdx.x == 0) cnt = 0;
  __syncthreads();
  int c = 0;
  for (int i = threadIdx.x; i < 8192; i += 256) {
    u16 x = win[i];
    int e = (x >> 7) & 0xFF;
    if (e != 0 && (e < 90 || e > 160)) c++;
  }
  atomicAdd(&cnt, c);
  __syncthreads();
  if (threadIdx.x == 0) *flag = (cnt > 512) ? 1 : 0;
}

// ---------------- convert small params to fp32 ws arrays ----------------
__device__ __forceinline__ float readin(const void* p, int i, int isf32) {
  return isf32 ? ((const float*)p)[i] : bf2f(((const u16*)p)[i]);
}
#define N_CW 16896
#define N_CB 4224
#define N_SMALL (N_CW + N_CB + 32 + 32 + 32 + 4096)
__global__ __launch_bounds__(256) void convert_small_k(const void* cw, const void* cb,
                                                       const void* dtb, const void* alog,
                                                       const void* Dv, const void* nw,
                                                       const int* __restrict__ flag,
                                                       float* __restrict__ dst) {
  int idx = blockIdx.x * 256 + threadIdx.x;
  if (idx >= N_SMALL) return;
  int f = *flag;
  float v; int o = idx;
  if (o < N_CW) { v = readin(cw, o, f); }
  else if ((o -= N_CW) < N_CB) { v = readin(cb, o, f); }
  else if ((o -= N_CB) < 32) { v = readin(dtb, o, f); }
  else if ((o -= 32) < 32) { v = readin(alog, o, f); }
  else if ((o -= 32) < 32) { v = readin(Dv, o, f); }
  else { o -= 32; v = readin(nw, o, f); }
  dst[idx] = v;
}

// ---------------- convert big tensor -> packed bf16 (zero-pad tail) ----------------
__global__ __launch_bounds__(256) void to_bf16_k(const void* __restrict__ src,
                                                 u16* __restrict__ dst,
                                                 long n_src, long n_total,
                                                 const int* __restrict__ flag) {
  long i = ((long)blockIdx.x * 256 + threadIdx.x) * 8;
  if (i >= n_total) return;
  ushort4 o0, o1;
  if (i >= n_src) {
    o0.x = o0.y = o0.z = o0.w = 0; o1 = o0;
  } else if (*flag) {
    float4 a = *((const float4*)src + (i >> 2));
    float4 b = *((const float4*)src + (i >> 2) + 1);
    o0.x = f2bf(a.x); o0.y = f2bf(a.y); o0.z = f2bf(a.z); o0.w = f2bf(a.w);
    o1.x = f2bf(b.x); o1.y = f2bf(b.y); o1.z = f2bf(b.z); o1.w = f2bf(b.w);
  } else {
    o0 = *((const ushort4*)src + (i >> 2));
    o1 = *((const ushort4*)src + (i >> 2) + 1);
  }
  *(ushort4*)(dst + i) = o0;
  *(ushort4*)(dst + i + 4) = o1;
}

// ---------------- 256x256 MFMA GEMM (r4-locked) ----------------
__device__ __forceinline__ void glds16(const u16* g, u16* l) {
  __builtin_amdgcn_global_load_lds((const __attribute__((address_space(1))) void*)g,
                                   (__attribute__((address_space(3))) void*)l, 16, 0, 0);
}

template <int OUTDYN>
__global__ __launch_bounds__(512, 2) void gemm256(const u16* __restrict__ A, int lda,
                                                  const u16* __restrict__ B, int ldb,
                                                  void* __restrict__ Cv, int ldc,
                                                  int M, int N, int K,
                                                  const int* __restrict__ flagp) {
  __shared__ __align__(16) u16 As[32768];   // 2 x [256 rows x 64 cols]
  __shared__ __align__(16) u16 Bs[32768];
  const int tid = threadIdx.x;
  const int lane = tid & 63, w = tid >> 6;
  const int wm = w >> 2, wn = w & 3;        // wave -> 128x64 output sub-tile

  const int gx = (int)gridDim.x;
  const int nwg = gx * (int)gridDim.y;
  const int phys = (int)blockIdx.y * gx + (int)blockIdx.x;
  const int logical = (phys & 7) * (nwg >> 3) + (phys >> 3);
  const int bm = (logical / gx) << 8;
  const int bn = (logical % gx) << 8;

  const int nk = K >> 6;        // K-tiles of 64
  const int smax = nk << 2;     // half-tile stream length (4 per K-tile)

  const int srow = tid >> 3;
  const int scol = ((tid & 7) ^ (srow & 7)) << 3;   // u16 col within 64
  const u16* agb = A + (size_t)(bm + srow) * lda + scol;
  const u16* bgb = B + (size_t)(bn + srow) * ldb + scol;
  const size_t a64 = (size_t)64 * lda, b64 = (size_t)64 * ldb;
  u16* asl = As + tid * 8;
  u16* bsl = Bs + tid * 8;

#define STAGE(sv) do { int s_ = (sv); if (s_ < smax) {                        \
    int kt_ = s_ >> 2, it_ = s_ & 3;                                          \
    int ko_ = kt_ << 6; int dbo_ = (kt_ & 1) << 14;                           \
    if (it_ < 2) {                                                            \
      const u16* g_ = agb + (size_t)(it_ << 7) * lda + ko_;                   \
      u16* l_ = asl + dbo_ + (it_ << 13);                                     \
      glds16(g_, l_); glds16(g_ + a64, l_ + 4096);                            \
    } else {                                                                  \
      const u16* g_ = bgb + (size_t)((it_ & 1) << 7) * ldb + ko_;             \
      u16* l_ = bsl + dbo_ + ((it_ & 1) << 13);                               \
      glds16(g_, l_); glds16(g_ + b64, l_ + 4096);                            \
    } } } while (0)

  f32x4 acc[8][4];
  #pragma unroll
  for (int i = 0; i < 8; ++i)
    #pragma unroll
    for (int n = 0; n < 4; ++n) { acc[i][n].x = 0.f; acc[i][n].y = 0.f; acc[i][n].z = 0.f; acc[i][n].w = 0.f; }

  STAGE(0); STAGE(1); STAGE(2); STAGE(3); STAGE(4); STAGE(5);
  asm volatile("s_waitcnt vmcnt(4)" ::: "memory");
  __builtin_amdgcn_s_barrier();

  const int m16 = lane & 15;
  const int rsw = (lane & 7) << 3;
  const int c0 = (((lane >> 4) << 3)) ^ rsw;
  const int c1 = (32 | ((lane >> 4) << 3)) ^ rsw;
  const int aRow = (((wm << 7) + m16) << 6);
  const int bRow = (((wn << 6) + m16) << 6);

  bf16x8 af[8][2], bfv[4][2];

  for (int j = 0; j < nk; ++j) {
    const int db = (j & 1) << 14;
    const u16* Ab = As + db + aRow;
    const u16* Bb = Bs + db + bRow;

    // phase 1
    #pragma unroll
    for (int i = 0; i < 4; ++i) {
      af[i][0] = *(const bf16x8*)(Ab + i * 1024 + c0);
      af[i][1] = *(const bf16x8*)(Ab + i * 1024 + c1);
    }
    #pragma unroll
    for (int n = 0; n < 2; ++n) {
      bfv[n][0] = *(const bf16x8*)(Bb + n * 1024 + c0);
      bfv[n][1] = *(const bf16x8*)(Bb + n * 1024 + c1);
    }
    __builtin_amdgcn_sched_barrier(0);
    STAGE((j << 2) + 6);
    __builtin_amdgcn_s_barrier();
    asm volatile("s_waitcnt lgkmcnt(0)" ::: "memory");
    __builtin_amdgcn_sched_barrier(0);
    __builtin_amdgcn_s_setprio(1);
    #pragma unroll
    for (int i = 0; i < 4; ++i)
      #pragma unroll
      for (int n = 0; n < 2; ++n) {
        acc[i][n] = __builtin_amdgcn_mfma_f32_16x16x32_bf16(af[i][0], bfv[n][0], acc[i][n], 0, 0, 0);
        acc[i][n] = __builtin_amdgcn_mfma_f32_16x16x32_bf16(af[i][1], bfv[n][1], acc[i][n], 0, 0, 0);
      }
    __builtin_amdgcn_s_setprio(0);
    __builtin_amdgcn_s_barrier();

    // phase 2
    #pragma unroll
    for (int i = 0; i < 4; ++i) {
      af[4 + i][0] = *(const bf16x8*)(Ab + 4096 + i * 1024 + c0);
      af[4 + i][1] = *(const bf16x8*)(Ab + 4096 + i * 1024 + c1);
    }
    #pragma unroll
    for (int n = 0; n < 2; ++n) {
      bfv[2 + n][0] = *(const bf16x8*)(Bb + 2048 + n * 1024 + c0);
      bfv[2 + n][1] = *(const bf16x8*)(Bb + 2048 + n * 1024 + c1);
    }
    __builtin_amdgcn_sched_barrier(0);
    STAGE((j << 2) + 7);
    __builtin_amdgcn_s_barrier();
    asm volatile("s_waitcnt lgkmcnt(0)" ::: "memory");
    __builtin_amdgcn_sched_barrier(0);
    __builtin_amdgcn_s_setprio(1);
    #pragma unroll
    for (int i = 4; i < 8; ++i)
      #pragma unroll
      for (int n = 2; n < 4; ++n) {
        acc[i][n] = __builtin_amdgcn_mfma_f32_16x16x32_bf16(af[i][0], bfv[n][0], acc[i][n], 0, 0, 0);
        acc[i][n] = __builtin_amdgcn_mfma_f32_16x16x32_bf16(af[i][1], bfv[n][1], acc[i][n], 0, 0, 0);
      }
    __builtin_amdgcn_s_setprio(0);
    __builtin_amdgcn_s_barrier();

    // phase 3
    STAGE((j << 2) + 8);
    __builtin_amdgcn_s_barrier();
    __builtin_amdgcn_s_setprio(1);
    #pragma unroll
    for (int i = 0; i < 4; ++i)
      #pragma unroll
      for (int n = 2; n < 4; ++n) {
        acc[i][n] = __builtin_amdgcn_mfma_f32_16x16x32_bf16(af[i][0], bfv[n][0], acc[i][n], 0, 0, 0);
        acc[i][n] = __builtin_amdgcn_mfma_f32_16x16x32_bf16(af[i][1], bfv[n][1], acc[i][n], 0, 0, 0);
      }
    __builtin_amdgcn_s_setprio(0);
    __builtin_amdgcn_s_barrier();

    // phase 4
    STAGE((j << 2) + 9);
    __builtin_amdgcn_s_barrier();
    __builtin_amdgcn_s_setprio(1);
    #pragma unroll
    for (int i = 4; i < 8; ++i)
      #pragma unroll
      for (int n = 0; n < 2; ++n) {
        acc[i][n] = __builtin_amdgcn_mfma_f32_16x16x32_bf16(af[i][0], bfv[n][0], acc[i][n], 0, 0, 0);
        acc[i][n] = __builtin_amdgcn_mfma_f32_16x16x32_bf16(af[i][1], bfv[n][1], acc[i][n], 0, 0, 0);
      }
    __builtin_amdgcn_s_setprio(0);
    if (j < nk - 2) {
      asm volatile("s_waitcnt vmcnt(4)" ::: "memory");
    } else if (j == nk - 2) {
      asm volatile("s_waitcnt vmcnt(0)" ::: "memory");
    }
    __builtin_amdgcn_s_barrier();
  }
#undef STAGE

  const int r4 = (lane >> 4) << 2;
  int f = 0;
  if (OUTDYN) f = *flagp;
  #pragma unroll
  for (int i = 0; i < 8; ++i) {
    #pragma unroll
    for (int r = 0; r < 4; ++r) {
      size_t rowoff = (size_t)(bm + (wm << 7) + i * 16 + r4 + r) * ldc;
      #pragma unroll
      for (int n = 0; n < 4; ++n) {
        int col = bn + (wn << 6) + n * 16 + m16;
        if (col < N) {
          float v = acc[i][n][r];
          if (OUTDYN && f) ((float*)Cv)[rowoff + col] = v;
          else             ((u16*)Cv)[rowoff + col] = f2bf(v);
        }
      }
    }
  }
}

// ---------------- causal conv4 + SiLU (vectorized x8) ----------------
__global__ __launch_bounds__(256) void conv_silu_k(const u16* __restrict__ zx,
                                                   const float* __restrict__ cwf,
                                                   const float* __restrict__ cbf,
                                                   u16* __restrict__ xBC) {
  int idx = blockIdx.x * 256 + threadIdx.x;   // 0..527
  if (idx >= (CONV_DIM / 8)) return;
  int c0 = idx << 3;
  int row = blockIdx.y;
  int b = row >> 12, l = row & 4095;
  float acc[8];
  #pragma unroll
  for (int j = 0; j < 8; ++j) acc[j] = cbf[c0 + j];
  #pragma unroll
  for (int k = 0; k < 4; ++k) {
    int li = l - 3 + k;
    if (li >= 0) {
      const u16* zp = zx + (size_t)(b * SEQLEN + li) * D_IN_PROJ + D_INNER + c0;
      ushort4 v0 = *(const ushort4*)zp;
      ushort4 v1 = *(const ushort4*)(zp + 4);
      float xv[8] = {bf2f(v0.x), bf2f(v0.y), bf2f(v0.z), bf2f(v0.w),
                     bf2f(v1.x), bf2f(v1.y), bf2f(v1.z), bf2f(v1.w)};
      #pragma unroll
      for (int j = 0; j < 8; ++j) acc[j] += xv[j] * cwf[(c0 + j) * 4 + k];
    }
  }
  ushort4 o0, o1;
  float a0 = acc[0] / (1.f + __expf(-acc[0])); o0.x = f2bf(a0);
  float a1 = acc[1] / (1.f + __expf(-acc[1])); o0.y = f2bf(a1);
  float a2 = acc[2] / (1.f + __expf(-acc[2])); o0.z = f2bf(a2);
  float a3 = acc[3] / (1.f + __expf(-acc[3])); o0.w = f2bf(a3);
  float a4 = acc[4] / (1.f + __expf(-acc[4])); o1.x = f2bf(a4);
  float a5 = acc[5] / (1.f + __expf(-acc[5])); o1.y = f2bf(a5);
  float a6 = acc[6] / (1.f + __expf(-acc[6])); o1.z = f2bf(a6);
  float a7 = acc[7] / (1.f + __expf(-acc[7])); o1.w = f2bf(a7);
  u16* dst = xBC + (size_t)row * CONV_DIM + c0;
  *(ushort4*)dst = o0;
  *(ushort4*)(dst + 4) = o1;
}

// ---------------- dt = softplus(raw + bias) ----------------
__global__ __launch_bounds__(256) void dt_softplus_k(const u16* __restrict__ zx,
                                                     const float* __restrict__ dtbf,
                                                     float* __restrict__ dtf) {
  int idx = blockIdx.x * 256 + threadIdx.x;   // ROWS*NHEADS
  int i = idx >> 5, h = idx & 31;
  float x = bf2f(zx[(size_t)i * D_IN_PROJ + (D_INNER + CONV_DIM) + h]) + dtbf[h];
  float sp = (x > 20.f) ? x : log1pf(__expf(fminf(x, 20.f)));
  dtf[idx] = sp;
}

// ---------------- per-chunk cum/decay + states via MFMA ----------------
// states[p][n] = sum_z x[z][p] * (w[z]*B[z][n]),  w[z]=exp(min(cl-cum[z],0))*dt[z]
// Parallel cumsum (shfl_up + cross-wave prefix) replaces the serial tid0 scan.
// A-tile x^T and B-tile (wB)^T staged via ydiag's proven scatter-transpose +
// slot swizzle; MFMA 2x2 waves, out 128x64, K=256 in 4 steps.
__global__ __launch_bounds__(256) void chunk_states_k(const u16* __restrict__ xBC,
                                                      const float* __restrict__ dtf,
                                                      const float* __restrict__ alogf,
                                                      float* __restrict__ cumf,
                                                      float* __restrict__ cdec,
                                                      float* __restrict__ states) {
  const int h = blockIdx.x, c = blockIdx.y, b = blockIdx.z;
  const int tid = threadIdx.x;
  const int lane = tid & 63, wv = tid >> 6;
  __shared__ __align__(16) u16 Ax[128 * 64];   // x^T [p][z], swizzled slots
  __shared__ __align__(16) u16 Bw[64 * 64];    // (w*B)^T [n][z], swizzled slots
  __shared__ __align__(16) float w_sh[CHUNK];
  __shared__ float wsum[4];
  const int rowbase = b * SEQLEN + c * CHUNK;
  const int hoff = h * D_HEAD;

  // ---- parallel inclusive cumsum of dA = dt*Aneg ----
  float dtv = dtf[(size_t)(rowbase + tid) * NHEADS + h];
  float Aneg = -__expf(alogf[h]);
  float sv = dtv * Aneg;
  #pragma unroll
  for (int off = 1; off < 64; off <<= 1) {
    float t = __shfl_up(sv, off);
    if (lane >= off) sv += t;
  }
  if (lane == 63) wsum[wv] = sv;
  __syncthreads();
  float pre = 0.f;
  #pragma unroll
  for (int q = 0; q < 4; ++q) pre += (q < wv) ? wsum[q] : 0.f;
  float cum = sv + pre;
  float cl = wsum[0] + wsum[1] + wsum[2] + wsum[3];
  w_sh[tid] = __expf(fminf(cl - cum, 0.f)) * dtv;
  cumf[((size_t)(b * NC + c) * NHEADS + h) * CHUNK + tid] = cum;
  if (tid == 0) cdec[(b * NC + c) * NHEADS + h] = __expf(fminf(cl, 0.f));

  f32x4 acc[4][2];
  #pragma unroll
  for (int i = 0; i < 4; ++i)
    #pragma unroll
    for (int n = 0; n < 2; ++n) { acc[i][n].x = 0.f; acc[i][n].y = 0.f; acc[i][n].z = 0.f; acc[i][n].w = 0.f; }

  const int m16 = lane & 15;
  const int rsw = (lane & 7) << 3;
  const int c0 = (((lane >> 4) << 3)) ^ rsw;
  const int c1 = (32 | ((lane >> 4) << 3)) ^ rsw;
  const int wm = wv >> 1, wn = wv & 1;   // wave -> 64(p) x 32(n) sub-tile

  for (int step = 0; step < 4; ++step) {
    __syncthreads();
    const int z0 = step << 6;
    // ---- Ax: x^T [p=128][z=64] via coalesced 16B reads + scatter transpose ----
    {
      const int zz = tid >> 2;            // z within tile
      const int ps = (tid & 3) << 5;      // p group of 32
      const u16* xg = xBC + (size_t)(rowbase + z0 + zz) * CONV_DIM + hoff + ps;
      bf16x8 va = *(const bf16x8*)xg;
      bf16x8 vb = *(const bf16x8*)(xg + 8);
      bf16x8 vc = *(const bf16x8*)(xg + 16);
      bf16x8 vd = *(const bf16x8*)(xg + 24);
      const int zhi = zz >> 3, zlo = zz & 7;
      #pragma unroll
      for (int q = 0; q < 4; ++q) {
        #pragma unroll
        for (int i2 = 0; i2 < 8; ++i2) {
          u16 val = (u16)(q == 0 ? va[i2] : q == 1 ? vb[i2] : q == 2 ? vc[i2] : vd[i2]);
          int p = ps + (q << 3) + i2;
          Ax[(p << 6) + ((zhi ^ (p & 7)) << 3) + zlo] = val;
        }
      }
    }
    // ---- Bw: (w*B)^T [n=64][z=64] ----
    {
      const int zz = tid >> 2;
      const int ns = (tid & 3) << 4;      // n group of 16
      const u16* bg = xBC + (size_t)(rowbase + z0 + zz) * CONV_DIM + D_INNER + ns;
      bf16x8 va = *(const bf16x8*)bg;
      bf16x8 vb = *(const bf16x8*)(bg + 8);
      float wz = w_sh[z0 + zz];
      const int zhi = zz >> 3, zlo = zz & 7;
      #pragma unroll
      for (int q = 0; q < 2; ++q) {
        #pragma unroll
        for (int i2 = 0; i2 < 8; ++i2) {
          u16 raw = (u16)(q == 0 ? va[i2] : vb[i2]);
          u16 val = f2bf(bf2f(raw) * wz);
          int n = ns + (q << 3) + i2;
          Bw[(n << 6) + ((zhi ^ (n & 7)) << 3) + zlo] = val;
        }
      }
    }
    __syncthreads();
    // ---- fragments + MFMA ----
    bf16x8 af[4][2], bfv[2][2];
    #pragma unroll
    for (int i = 0; i < 4; ++i) {
      const u16* base = Ax + ((((wm << 6) + (i << 4) + m16)) << 6);
      af[i][0] = *(const bf16x8*)(base + c0);
      af[i][1] = *(const bf16x8*)(base + c1);
    }
    #pragma unroll
    for (int n = 0; n < 2; ++n) {
      const u16* base = Bw + ((((wn << 5) + (n << 4) + m16)) << 6);
      bfv[n][0] = *(const bf16x8*)(base + c0);
      bfv[n][1] = *(const bf16x8*)(base + c1);
    }
    #pragma unroll
    for (int k = 0; k < 2; ++k)
      #pragma unroll
      for (int i = 0; i < 4; ++i)
        #pragma unroll
        for (int n = 0; n < 2; ++n)
          acc[i][n] = __builtin_amdgcn_mfma_f32_16x16x32_bf16(af[i][k], bfv[n][k], acc[i][n], 0, 0, 0);
  }

  // ---- store states [p][n] fp32 (C/D: col=lane&15, row=(lane>>4)*4+reg) ----
  float* sp = states + ((size_t)(b * NC + c) * NHEADS + h) * (D_HEAD * D_STATE);
  const int r4 = (lane >> 4) << 2;
  #pragma unroll
  for (int i = 0; i < 4; ++i) {
    #pragma unroll
    for (int r = 0; r < 4; ++r) {
      int p = (wm << 6) + (i << 4) + r4 + r;
      #pragma unroll
      for (int n = 0; n < 2; ++n) {
        int nn = (wn << 5) + (n << 4) + m16;
        sp[(size_t)p * D_STATE + nn] = acc[i][n][r];
      }
    }
  }
}

// ---------------- inter-chunk scan (pipelined: prefetch c+1 under carry) ----------------
__global__ __launch_bounds__(256) void scan_k(float* __restrict__ states,
                                              const float* __restrict__ cdec) {
  const int g = blockIdx.x, h = blockIdx.y, b = blockIdx.z;
  const int tid = threadIdx.x;
  const int e0 = (g << 10) + tid;
  const size_t cstride = (size_t)NHEADS * (D_HEAD * D_STATE);   // floats per chunk step
  float dec[NC];
  #pragma unroll
  for (int c = 0; c < NC; ++c) dec[c] = cdec[(b * NC + c) * NHEADS + h];
  float carry[4];
  #pragma unroll
  for (int j = 0; j < 4; ++j) carry[j] = 0.f;
  size_t base = ((size_t)(b * NC + 0) * NHEADS + h) * (D_HEAD * D_STATE) + e0;
  float scur[4];
  #pragma unroll
  for (int j = 0; j < 4; ++j) scur[j] = states[base + (j << 8)];
  for (int c = 0; c < NC; ++c) {
    float snx[4];
    if (c + 1 < NC) {
      #pragma unroll
      for (int j = 0; j < 4; ++j) snx[j] = states[base + cstride + (j << 8)];
    }
    #pragma unroll
    for (int j = 0; j < 4; ++j) {
      states[base + (j << 8)] = carry[j];
      carry[j] = carry[j] * dec[c] + scur[j];
    }
    #pragma unroll
    for (int j = 0; j < 4; ++j) scur[j] = snx[j];
    base += cstride;
  }
}

// ---------------- scores = C . B^T ----------------
__global__ __launch_bounds__(256) void scores_k(const u16* __restrict__ xBC,
                                                float* __restrict__ scores) {
  const int bx = blockIdx.x;            // 0..15
  const int c = blockIdx.y, b = blockIdx.z;
  const int s0 = (bx >> 2) << 6, z0 = (bx & 3) << 6;
  __shared__ __align__(16) float Cs[64][68];   // [n][s]
  __shared__ __align__(16) float Bs2[64][68];  // [n][z]
  const int tid = threadIdx.x;
  const int rowbase = b * SEQLEN + c * CHUNK;
  int r = tid >> 2, nq = (tid & 3) << 4;
  const u16* cp = xBC + (size_t)(rowbase + s0 + r) * CONV_DIM + D_INNER + D_STATE + nq;
  const u16* bp = xBC + (size_t)(rowbase + z0 + r) * CONV_DIM + D_INNER + nq;
  #pragma unroll
  for (int q = 0; q < 16; q += 4) {
    ushort4 v = *(const ushort4*)(cp + q);
    Cs[nq+q+0][r] = bf2f(v.x); Cs[nq+q+1][r] = bf2f(v.y);
    Cs[nq+q+2][r] = bf2f(v.z); Cs[nq+q+3][r] = bf2f(v.w);
    ushort4 w2 = *(const ushort4*)(bp + q);
    Bs2[nq+q+0][r] = bf2f(w2.x); Bs2[nq+q+1][r] = bf2f(w2.y);
    Bs2[nq+q+2][r] = bf2f(w2.z); Bs2[nq+q+3][r] = bf2f(w2.w);
  }
  __syncthreads();
  const int tx = tid & 15, ty = tid >> 4;
  float acc[4][4];
  #pragma unroll
  for (int i = 0; i < 4; ++i)
    #pragma unroll
    for (int j = 0; j < 4; ++j) acc[i][j] = 0.f;
  #pragma unroll 8
  for (int n = 0; n < 64; ++n) {
    float4 a = *(const float4*)&Cs[n][ty << 2];
    float4 bb = *(const float4*)&Bs2[n][tx << 2];
    float av[4] = {a.x, a.y, a.z, a.w};
    float bv[4] = {bb.x, bb.y, bb.z, bb.w};
    #pragma unroll
    for (int i = 0; i < 4; ++i)
      #pragma unroll
      for (int j = 0; j < 4; ++j) acc[i][j] += av[i] * bv[j];
  }
  float* spp = scores + (size_t)(b * NC + c) * CHUNK * CHUNK;
  #pragma unroll
  for (int i = 0; i < 4; ++i)
    #pragma unroll
    for (int j = 0; j < 4; ++j)
      spp[(size_t)(s0 + (ty << 2) + i) * CHUNK + z0 + (tx << 2) + j] = acc[i][j];
}

// ---------------- Y via MFMA: (scores*L*dt)@x^T + exp(cum)*C@prev^T + D*x ----------------
__global__ __launch_bounds__(256) void ydiag_mfma_k(const u16* __restrict__ xBC,
                                                    const float* __restrict__ dtf,
                                                    const float* __restrict__ cumf,
                                                    const float* __restrict__ scores,
                                                    const float* __restrict__ prevst,
                                                    const float* __restrict__ df,
                                                    u16* __restrict__ y) {
  const int h = blockIdx.x, c = blockIdx.y, b = blockIdx.z;
  const int tid = threadIdx.x;
  const int lane = tid & 63, w = tid >> 6;
  const int wm = w >> 1, wn = w & 1;          // wave -> 128x64 of 256x128 out
  __shared__ __align__(16) u16 Pl[256 * 64];  // A-tile [s][64], swizzled slots
  __shared__ __align__(16) u16 Xl[128 * 64];  // B-tile [p][64], swizzled slots
  __shared__ __align__(16) float cum_sh[CHUNK];
  __shared__ __align__(16) float dts[CHUNK];
  const int rowbase = b * SEQLEN + c * CHUNK;
  const int hoff = h * D_HEAD;
  cum_sh[tid] = cumf[((size_t)(b * NC + c) * NHEADS + h) * CHUNK + tid];
  dts[tid] = dtf[(size_t)(rowbase + tid) * NHEADS + h];
  const float* scb = scores + (size_t)(b * NC + c) * CHUNK * CHUNK;
  const float* prevb = prevst + ((size_t)(b * NC + c) * NHEADS + h) * (D_HEAD * D_STATE);

  f32x4 acc[8][4];
  #pragma unroll
  for (int i = 0; i < 8; ++i)
    #pragma unroll
    for (int n = 0; n < 4; ++n) { acc[i][n].x = 0.f; acc[i][n].y = 0.f; acc[i][n].z = 0.f; acc[i][n].w = 0.f; }

  const int m16 = lane & 15;
  const int rsw = (lane & 7) << 3;
  const int c0 = (((lane >> 4) << 3)) ^ rsw;
  const int c1 = (32 | ((lane >> 4) << 3)) ^ rsw;

  for (int step = 0; step < 5; ++step) {
    __syncthreads();
    if (step < 4) {
      const int z0 = step << 6;
      // ---- P~ staging: 8 coalesced row-passes (8 lanes per row) ----
      {
        const int sr = tid >> 3;            // 0..31
        const int zq = (tid & 7) << 3;      // col group
        #pragma unroll
        for (int pp = 0; pp < 8; ++pp) {
          int s = (pp << 5) + sr;
          float cs = cum_sh[s];
          const float* srow = scb + (size_t)s * CHUNK + z0 + zq;
          float4 fa = *(const float4*)srow;
          float4 fb = *(const float4*)(srow + 4);
          float fv[8] = {fa.x, fa.y, fa.z, fa.w, fb.x, fb.y, fb.z, fb.w};
          u16 e[8];
          #pragma unroll
          for (int i2 = 0; i2 < 8; ++i2) {
            int z = z0 + zq + i2;
            float val = (z <= s) ? fv[i2] * __expf(fminf(cs - cum_sh[z], 0.f)) * dts[z] : 0.f;
            e[i2] = f2bf(val);
          }
          ushort4 lo, hi;
          lo.x = e[0]; lo.y = e[1]; lo.z = e[2]; lo.w = e[3];
          hi.x = e[4]; hi.y = e[5]; hi.z = e[6]; hi.w = e[7];
          u16* dst = Pl + (s << 6) + ((((zq >> 3) ^ (s & 7))) << 3);
          *(ushort4*)dst = lo; *(ushort4*)(dst + 4) = hi;
        }
      }
      // ---- Xt staging: coalesced 16B reads of x[z][p], LDS scatter transpose ----
      {
        const int zz = tid >> 2;            // 0..63 (z within tile)
        const int ps = (tid & 3) << 5;      // p group of 32
        const u16* xg = xBC + (size_t)(rowbase + z0 + zz) * CONV_DIM + hoff + ps;
        bf16x8 va = *(const bf16x8*)xg;
        bf16x8 vb = *(const bf16x8*)(xg + 8);
        bf16x8 vc = *(const bf16x8*)(xg + 16);
        bf16x8 vd = *(const bf16x8*)(xg + 24);
        const int zhi = (zz >> 3), zlo = zz & 7;
        #pragma unroll
        for (int q = 0; q < 4; ++q) {
          #pragma unroll
          for (int i2 = 0; i2 < 8; ++i2) {
            u16 val = (u16)(q == 0 ? va[i2] : q == 1 ? vb[i2] : q == 2 ? vc[i2] : vd[i2]);
            int p = ps + (q << 3) + i2;
            Xl[(p << 6) + ((zhi ^ (p & 7)) << 3) + zlo] = val;
          }
        }
      }
    } else {
      // ---- off staging: A2[s][n] = exp(cum[s])*C[s,n] (coalesced row-passes) ----
      {
        const int sr = tid >> 3;
        const int nq = (tid & 7) << 3;
        #pragma unroll
        for (int pp = 0; pp < 8; ++pp) {
          int s = (pp << 5) + sr;
          float es = __expf(fminf(cum_sh[s], 0.f));
          const u16* crow = xBC + (size_t)(rowbase + s) * CONV_DIM + D_INNER + D_STATE + nq;
          ushort4 a = *(const ushort4*)crow;
          ushort4 b4 = *(const ushort4*)(crow + 4);
          ushort4 lo, hi;
          lo.x = f2bf(bf2f(a.x) * es); lo.y = f2bf(bf2f(a.y) * es);
          lo.z = f2bf(bf2f(a.z) * es); lo.w = f2bf(bf2f(a.w) * es);
          hi.x = f2bf(bf2f(b4.x) * es); hi.y = f2bf(bf2f(b4.y) * es);
          hi.z = f2bf(bf2f(b4.z) * es); hi.w = f2bf(bf2f(b4.w) * es);
          u16* dst = Pl + (s << 6) + ((((nq >> 3) ^ (s & 7))) << 3);
          *(ushort4*)dst = lo; *(ushort4*)(dst + 4) = hi;
        }
      }
      // ---- B2[p][n] = prev[p,n] (natural layout, row-coalesced) ----
      {
        const int p = tid >> 1;
        const float* pr = prevb + (size_t)p * D_STATE;
        u16* xrow = Xl + (p << 6);
        #pragma unroll
        for (int kk = 0; kk < 4; ++kk) {
          int q = ((tid & 1) << 2) + kk;
          float4 f0 = *(const float4*)(pr + (q << 3));
          float4 f1 = *(const float4*)(pr + (q << 3) + 4);
          ushort4 lo, hi;
          lo.x = f2bf(f0.x); lo.y = f2bf(f0.y); lo.z = f2bf(f0.z); lo.w = f2bf(f0.w);
          hi.x = f2bf(f1.x); hi.y = f2bf(f1.y); hi.z = f2bf(f1.z); hi.w = f2bf(f1.w);
          u16* dst = xrow + ((q ^ (p & 7)) << 3);
          *(ushort4*)dst = lo; *(ushort4*)(dst + 4) = hi;
        }
      }
    }
    __syncthreads();
    // ---- fragments + MFMA ----
    bf16x8 af[8][2], bfv[4][2];
    #pragma unroll
    for (int i = 0; i < 8; ++i) {
      const u16* base = Pl + ((((wm << 7) + (i << 4) + m16)) << 6);
      af[i][0] = *(const bf16x8*)(base + c0);
      af[i][1] = *(const bf16x8*)(base + c1);
    }
    #pragma unroll
    for (int n = 0; n < 4; ++n) {
      const u16* base = Xl + ((((wn << 6) + (n << 4) + m16)) << 6);
      bfv[n][0] = *(const bf16x8*)(base + c0);
      bfv[n][1] = *(const bf16x8*)(base + c1);
    }
    #pragma unroll
    for (int k = 0; k < 2; ++k)
      #pragma unroll
      for (int i = 0; i < 8; ++i)
        #pragma unroll
        for (int n = 0; n < 4; ++n)
          acc[i][n] = __builtin_amdgcn_mfma_f32_16x16x32_bf16(af[i][k], bfv[n][k], acc[i][n], 0, 0, 0);
  }

  // epilogue: + D*x, store bf16.  C/D layout: col = lane&15, row = (lane>>4)*4 + reg
  const float Dvv = df[h];
  const int r4 = (lane >> 4) << 2;
  #pragma unroll
  for (int i = 0; i < 8; ++i) {
    #pragma unroll
    for (int r = 0; r < 4; ++r) {
      int srow2 = (wm << 7) + (i << 4) + r4 + r;
      size_t grow = (size_t)(rowbase + srow2);
      #pragma unroll
      for (int n = 0; n < 4; ++n) {
        int p = (wn << 6) + (n << 4) + m16;
        float v = acc[i][n][r] + bf2f(xBC[grow * CONV_DIM + hoff + p]) * Dvv;
        y[grow * D_IN_PROJ + D_INNER + hoff + p] = f2bf(v);
      }
    }
  }
}

// ---------------- gating + RMSNorm (vectorized x8, in-place) ----------------
__global__ __launch_bounds__(256) void gatenorm_k(u16* __restrict__ zx,
                                                  const float* __restrict__ nwf) {
  const int row = blockIdx.x;
  const int tid = threadIdx.x;
  u16* zrow = zx + (size_t)row * D_IN_PROJ;
  u16* yrow = zrow + D_INNER;
  float vals[16];
  float ss = 0.f;
  #pragma unroll
  for (int q = 0; q < 2; ++q) {
    int e8 = (tid + (q << 8)) << 3;
    ushort4 y0 = *(const ushort4*)(yrow + e8);
    ushort4 y1 = *(const ushort4*)(yrow + e8 + 4);
    ushort4 z0 = *(const ushort4*)(zrow + e8);
    ushort4 z1 = *(const ushort4*)(zrow + e8 + 4);
    float yv[8] = {bf2f(y0.x), bf2f(y0.y), bf2f(y0.z), bf2f(y0.w),
                   bf2f(y1.x), bf2f(y1.y), bf2f(y1.z), bf2f(y1.w)};
    float zv[8] = {bf2f(z0.x), bf2f(z0.y), bf2f(z0.z), bf2f(z0.w),
                   bf2f(z1.x), bf2f(z1.y), bf2f(z1.z), bf2f(z1.w)};
    #pragma unroll
    for (int j = 0; j < 8; ++j) {
      float g = yv[j] * (zv[j] / (1.f + __expf(-zv[j])));
      vals[q * 8 + j] = g;
      ss += g * g;
    }
  }
  #pragma unroll
  for (int off = 1; off < 64; off <<= 1) ss += __shfl_xor(ss, off);
  __shared__ float red[4];
  int lane = tid & 63, wv = tid >> 6;
  if (lane == 0) red[wv] = ss;
  __syncthreads();
  float tot = red[0] + red[1] + red[2] + red[3];
  float scale = rsqrtf(tot * (1.f / D_INNER) + EPS_F);
  #pragma unroll
  for (int q = 0; q < 2; ++q) {
    int e8 = (tid + (q << 8)) << 3;
    ushort4 o0, o1;
    o0.x = f2bf(vals[q*8+0] * scale * nwf[e8+0]);
    o0.y = f2bf(vals[q*8+1] * scale * nwf[e8+1]);
    o0.z = f2bf(vals[q*8+2] * scale * nwf[e8+2]);
    o0.w = f2bf(vals[q*8+3] * scale * nwf[e8+3]);
    o1.x = f2bf(vals[q*8+4] * scale * nwf[e8+4]);
    o1.y = f2bf(vals[q*8+5] * scale * nwf[e8+5]);
    o1.z = f2bf(vals[q*8+6] * scale * nwf[e8+6]);
    o1.w = f2bf(vals[q*8+7] * scale * nwf[e8+7]);
    *(ushort4*)(yrow + e8) = o0;
    *(ushort4*)(yrow + e8 + 4) = o1;
  }
}

extern "C" void kernel_launch(void* const* d_in, const int* in_sizes, int n_in,
                              void* d_out, int out_size, void* d_ws, size_t ws_size,
                              hipStream_t stream) {
  (void)in_sizes; (void)n_in; (void)out_size; (void)ws_size;
  const void* u       = d_in[0];
  const void* W_in    = d_in[1];
  const void* conv_w  = d_in[2];
  const void* conv_b  = d_in[3];
  const void* dt_bias = d_in[4];
  const void* A_log   = d_in[5];
  const void* Dv      = d_in[6];
  const void* norm_w  = d_in[7];
  const void* W_out   = d_in[8];

  const long N_U    = (long)ROWS * D_MODEL;
  const long N_WIN  = (long)D_IN_PROJ * D_MODEL;
  const long N_WINP = (long)NPAD * D_MODEL;
  const long N_WOUT = (long)D_MODEL * D_INNER;

  char* w = (char*)d_ws;
  size_t o = 0;
  int*   flag  = (int*)(w + o);    o += 256;
  float* smallp= (float*)(w + o);  o += ((size_t)N_SMALL * 4 + 255) & ~(size_t)255;
  u16* zx      = (u16*)(w + o);    o += (size_t)ROWS * D_IN_PROJ * 2;
  u16* r2      = (u16*)(w + o);    o += (size_t)ROWS * CONV_DIM * 2;
  char* r3     = (char*)(w + o);   o += (size_t)BATCH * NC * NHEADS * D_HEAD * D_STATE * 4;
  float* dtf   = (float*)(w + o);  o += (size_t)ROWS * NHEADS * 4;
  float* cumf  = (float*)(w + o);  o += (size_t)BATCH * NC * NHEADS * CHUNK * 4;
  float* cdec  = (float*)(w + o);  o += ((size_t)BATCH * NC * NHEADS * 4 + 255) & ~(size_t)255;
  float* scores= (float*)(w + o);  o += (size_t)BATCH * NC * CHUNK * CHUNK * 4;

  u16* Win_b  = r2;
  u16* xbc    = r2;
  u16* Wout_b = r2;
  u16* u_b    = (u16*)r3;
  float* states = (float*)r3;

  float* cwf  = smallp;
  float* cbf  = smallp + N_CW;
  float* dtbf = cbf + N_CB;
  float* alogf= dtbf + 32;
  float* df   = alogf + 32;
  float* nwf  = df + 32;

  detect_k<<<1, 256, 0, stream>>>((const u16*)W_in, flag);
  convert_small_k<<<(N_SMALL + 255) / 256, 256, 0, stream>>>(
      conv_w, conv_b, dt_bias, A_log, Dv, norm_w, flag, smallp);
  to_bf16_k<<<(int)((N_U / 8 + 255) / 256), 256, 0, stream>>>(u, u_b, N_U, N_U, flag);
  to_bf16_k<<<(int)((N_WINP / 8 + 255) / 256), 256, 0, stream>>>(W_in, Win_b, N_WIN, N_WINP, flag);

  // 1. in_proj
  gemm256<0><<<dim3(NPAD / 256, ROWS / 256), 512, 0, stream>>>(
      u_b, D_MODEL, Win_b, D_MODEL, zx, D_IN_PROJ, ROWS, D_IN_PROJ, D_MODEL, flag);
  // 2. conv + silu
  conv_silu_k<<<dim3((CONV_DIM / 8 + 255) / 256, ROWS), 256, 0, stream>>>(zx, cwf, cbf, xbc);
  // 3. dt softplus
  dt_softplus_k<<<dim3(ROWS * NHEADS / 256), 256, 0, stream>>>(zx, dtbf, dtf);
  // 4. chunk states (MFMA + parallel cumsum)
  chunk_states_k<<<dim3(NHEADS, NC, BATCH), 256, 0, stream>>>(xbc, dtf, alogf, cumf, cdec, states);
  // 5. scan (pipelined)
  scan_k<<<dim3(8, NHEADS, BATCH), 256, 0, stream>>>(states, cdec);
  // 6. scores
  scores_k<<<dim3(16, NC, BATCH), 256, 0, stream>>>(xbc, scores);
  // 7. Y via MFMA
  ydiag_mfma_k<<<dim3(NHEADS, NC, BATCH), 256, 0, stream>>>(
      xbc, dtf, cumf, scores, states, df, zx);
  // 7.5 convert W_out
  to_bf16_k<<<(int)((N_WOUT / 8 + 255) / 256), 256, 0, stream>>>(W_out, Wout_b, N_WOUT, N_WOUT, flag);
  // 8. gate + norm
  gatenorm_k<<<dim3(ROWS), 256, 0, stream>>>(zx, nwf);
  // 9. out_proj
  gemm256<1><<<dim3(D_MODEL / 256, ROWS / 256), 512, 0, stream>>>(
      zx + D_INNER, D_IN_PROJ, Wout_b, D_INNER, d_out, D_MODEL, ROWS, D_MODEL, D_INNER, flag);
}